// Round 2
// baseline (264.424 us; speedup 1.0000x reference)
//
#include <hip/hip_runtime.h>
#include <float.h>

// ---------------------------------------------------------------------------
// Problem: B=1, N=10000, A=32, D=256, H=4, DH=64
// out = softmax((x@Wq) . gather(x@Wkv)[:,:256]) @ gather(x@Wkv)[:,256:] @ Wo + bo
// Restructure: project FIRST (x @ Wkv once), gather K/V rows by index after.
// ---------------------------------------------------------------------------

#define BM 128
#define BN 128
#define BK 16

// Classic fp32 SGEMM: C[M,N] = A[M,K] @ B[K,N] (+bias). 256 thr, 8x8/thread.
__global__ __launch_bounds__(256) void sgemm_kernel(
    const float* __restrict__ A, const float* __restrict__ B,
    float* __restrict__ C, const float* __restrict__ bias,
    int M, int N, int K)
{
    __shared__ float As[BK][BM + 4];   // +4 keeps 16B alignment, breaks bank stride
    __shared__ float Bs[BK][BN + 4];
    const int tid = threadIdx.x;
    const int tx = tid & 15;
    const int ty = tid >> 4;
    const int brow = blockIdx.y * BM;
    const int bcol = blockIdx.x * BN;

    float acc[8][8];
#pragma unroll
    for (int i = 0; i < 8; i++)
#pragma unroll
        for (int j = 0; j < 8; j++) acc[i][j] = 0.0f;

    for (int kk = 0; kk < K; kk += BK) {
        // A tile: BM x BK, stored transposed As[k][m]
#pragma unroll
        for (int i = 0; i < 2; i++) {
            int li = tid + i * 256;          // 0..511
            int r  = li >> 2;                // 0..127
            int c4 = (li & 3) * 4;           // 0,4,8,12
            int gr = brow + r; gr = gr < M ? gr : M - 1;   // clamp (stores guarded)
            float4 a4 = *(const float4*)(A + (size_t)gr * K + kk + c4);
            As[c4 + 0][r] = a4.x; As[c4 + 1][r] = a4.y;
            As[c4 + 2][r] = a4.z; As[c4 + 3][r] = a4.w;
        }
        // B tile: BK x BN
#pragma unroll
        for (int i = 0; i < 2; i++) {
            int li = tid + i * 256;
            int r  = li >> 5;                // 0..15
            int c  = (li & 31) * 4;          // 0..124
            *(float4*)(&Bs[r][c]) = *(const float4*)(B + (size_t)(kk + r) * N + bcol + c);
        }
        __syncthreads();
#pragma unroll
        for (int k = 0; k < BK; k++) {
            float a[8], b[8];
            *(float4*)(a)     = *(const float4*)(&As[k][ty * 8]);
            *(float4*)(a + 4) = *(const float4*)(&As[k][ty * 8 + 4]);
            *(float4*)(b)     = *(const float4*)(&Bs[k][tx * 8]);
            *(float4*)(b + 4) = *(const float4*)(&Bs[k][tx * 8 + 4]);
#pragma unroll
            for (int i = 0; i < 8; i++)
#pragma unroll
                for (int j = 0; j < 8; j++)
                    acc[i][j] = fmaf(a[i], b[j], acc[i][j]);
        }
        __syncthreads();
    }

#pragma unroll
    for (int i = 0; i < 8; i++) {
        int row = brow + ty * 8 + i;
        if (row < M) {
#pragma unroll
            for (int j = 0; j < 8; j += 4) {
                int col = bcol + tx * 8 + j;
                float4 o;
                o.x = acc[i][j + 0]; o.y = acc[i][j + 1];
                o.z = acc[i][j + 2]; o.w = acc[i][j + 3];
                if (bias) {
                    o.x += bias[col + 0]; o.y += bias[col + 1];
                    o.z += bias[col + 2]; o.w += bias[col + 3];
                }
                *(float4*)(C + (size_t)row * N + col) = o;
            }
        }
    }
}

// ---------------------------------------------------------------------------
// Attention: 1 block per query row n (256 thr = 4 waves, wave h = head h).
// Within a wave: 4 groups of 16 lanes; group g handles keys a = g, g+4, ...
// (33 keys: null + 32 gathered). Q/K dot via float4 + 4-step shfl_xor reduce.
// KV layout: row j = [K(256) | V(256)], col c = h*64 + dh.
// ---------------------------------------------------------------------------
__global__ __launch_bounds__(256) void attn_kernel(
    const float* __restrict__ Q, const float* __restrict__ KV,
    const int* __restrict__ aidx, const int* __restrict__ amask,
    const float* __restrict__ nullk, const float* __restrict__ nullv,
    float* __restrict__ out)
{
    const int n    = blockIdx.x;
    const int tid  = threadIdx.x;
    const int h    = tid >> 6;
    const int lane = tid & 63;
    const int g    = lane >> 4;   // key-group 0..3
    const int gl   = lane & 15;   // lane within group

    __shared__ int sidx[32];
    __shared__ int smask[32];
    if (tid < 32) { sidx[tid] = aidx[n * 32 + tid]; smask[tid] = amask[n * 32 + tid]; }
    __syncthreads();

    const float scale = 0.125f;   // 64^-0.5
    float4 q4 = ((const float4*)Q)[(size_t)n * 64 + h * 16 + gl];
    q4.x *= scale; q4.y *= scale; q4.z *= scale; q4.w *= scale;

    // --- scores: sim[r] holds a = r*4+g ---
    float sim[9];
#pragma unroll
    for (int r = 0; r < 9; r++) sim[r] = -3.0e38f;

#pragma unroll
    for (int r = 0; r < 9; r++) {
        int a = r * 4 + g;
        if (a < 33) {
            bool doit; float4 k4;
            if (a == 0) {
                doit = true;
                k4 = ((const float4*)nullk)[h * 16 + gl];
            } else {
                doit = (smask[a - 1] != 0);
                if (doit) {
                    int j = sidx[a - 1];
                    k4 = ((const float4*)KV)[(size_t)j * 128 + h * 16 + gl];
                }
            }
            if (doit) {
                float s = q4.x * k4.x + q4.y * k4.y + q4.z * k4.z + q4.w * k4.w;
                s += __shfl_xor(s, 1); s += __shfl_xor(s, 2);
                s += __shfl_xor(s, 4); s += __shfl_xor(s, 8);
                sim[r] = s;
            }
        }
    }

    // --- softmax over 33 keys (groups disjoint; lanes within group identical) ---
    float m = -3.0e38f;
#pragma unroll
    for (int r = 0; r < 9; r++) m = fmaxf(m, sim[r]);
    m = fmaxf(m, __shfl_xor(m, 16));
    m = fmaxf(m, __shfl_xor(m, 32));

    float p[9]; float l = 0.0f;
#pragma unroll
    for (int r = 0; r < 9; r++) {
        p[r] = (sim[r] > -1.0e37f) ? __expf(sim[r] - m) : 0.0f;
        l += p[r];
    }
    l += __shfl_xor(l, 16);
    l += __shfl_xor(l, 32);
    float inv = 1.0f / l;     // null key always present -> l > 0
#pragma unroll
    for (int r = 0; r < 9; r++) p[r] *= inv;

    // --- P @ V: each lane owns output dim d = lane ---
    float acc = 0.0f;
    float p0 = __shfl(p[0], 0);                    // a=0 lives in group 0, r=0
    acc += p0 * nullv[h * 64 + lane];
#pragma unroll
    for (int a = 1; a <= 32; a++) {
        float pa = __shfl(p[a >> 2], (a & 3) << 4);
        if (pa != 0.0f) {                          // wave-uniform; skips masked gathers
            int j = sidx[a - 1];
            acc += pa * KV[(size_t)j * 512 + 256 + h * 64 + lane];
        }
    }
    out[(size_t)n * 256 + h * 64 + lane] = acc;
}

// ---------------------------------------------------------------------------
extern "C" void kernel_launch(void* const* d_in, const int* in_sizes, int n_in,
                              void* d_out, int out_size, void* d_ws, size_t ws_size,
                              hipStream_t stream)
{
    const float* x     = (const float*)d_in[0];
    const int*   aidx  = (const int*)  d_in[1];
    const int*   amask = (const int*)  d_in[2];
    const float* Wq    = (const float*)d_in[3];
    const float* Wkv   = (const float*)d_in[4];
    const float* Wo    = (const float*)d_in[5];
    const float* bo    = (const float*)d_in[6];
    const float* nk    = (const float*)d_in[7];
    const float* nv    = (const float*)d_in[8];
    float* out = (float*)d_out;

    const int N = 10000;
    float* Q  = (float*)d_ws;                  // N*256 f32
    float* KV = Q  + (size_t)N * 256;          // N*512 f32
    float* AO = KV + (size_t)N * 512;          // N*256 f32

    const int gm = (N + BM - 1) / BM;          // 79
    dim3 blk(256);
    sgemm_kernel<<<dim3(2, gm), blk, 0, stream>>>(x,  Wq,  Q,   nullptr, N, 256, 256);
    sgemm_kernel<<<dim3(4, gm), blk, 0, stream>>>(x,  Wkv, KV,  nullptr, N, 512, 256);
    attn_kernel  <<<dim3(N),     blk, 0, stream>>>(Q, KV, aidx, amask, nk, nv, AO);
    sgemm_kernel<<<dim3(2, gm), blk, 0, stream>>>(AO, Wo,  out, bo,      N, 256, 256);
}

// Round 4
// 183.282 us; speedup vs baseline: 1.4427x; 1.4427x over previous
//
#include <hip/hip_runtime.h>
#include <float.h>

// ---------------------------------------------------------------------------
// B=1, N=10000, A=32, D=256, H=4, DH=64
// Restructure: project first (KV = x@Wkv once), gather rows after.
// Round 3: f16 MFMA GEMMs (16x16x16f16, classic verified layout) + f16 KV/Q
// tables to halve the attention gather footprint.
// ---------------------------------------------------------------------------

typedef _Float16 f16;
typedef _Float16 f16x4 __attribute__((ext_vector_type(4)));
typedef _Float16 f16x8 __attribute__((ext_vector_type(8)));
typedef float    f32x4 __attribute__((ext_vector_type(4)));

#define GBM 64
#define GBN 64
#define GBK 32
#define LDK 40   // padded LDS k-stride (f16) -> 80B row stride, conflict-lite

// f32 -> f16 cast, 4 elems/thread
__global__ __launch_bounds__(256) void cast_kernel(
    const float* __restrict__ in, f16* __restrict__ out, int n4)
{
    int i = blockIdx.x * 256 + threadIdx.x;
    if (i < n4) {
        float4 v = ((const float4*)in)[i];
        f16x4 o = {(f16)v.x, (f16)v.y, (f16)v.z, (f16)v.w};
        ((f16x4*)out)[i] = o;
    }
}

// W [K][Nn] f32 -> Wt [Nn][K] f16 (scaled). 32x32 LDS tile transpose.
__global__ __launch_bounds__(256) void tcast_kernel(
    const float* __restrict__ W, f16* __restrict__ Wt, int K, int Nn, float mul)
{
    __shared__ float s[32][33];
    const int tx = threadIdx.x & 31, ty = threadIdx.x >> 5;
    const int kb = blockIdx.y * 32, nb = blockIdx.x * 32;
#pragma unroll
    for (int r = 0; r < 4; r++)
        s[ty + r * 8][tx] = W[(size_t)(kb + ty + r * 8) * Nn + nb + tx];
    __syncthreads();
#pragma unroll
    for (int r = 0; r < 4; r++)
        Wt[(size_t)(nb + ty + r * 8) * K + kb + tx] = (f16)(s[tx][ty + r * 8] * mul);
}

// C[M][Nn] = A[M][K]f16 @ Bt[Nn][K]f16^T (+bias). 256 thr = 4 waves.
// Wave w owns rows w*16..w*16+15; 4 col-frags of 16. v_mfma_f32_16x16x16_f16:
//   A frag: lane l elem e -> A[l&15][4*(l>>4)+e]
//   B frag: lane l elem e -> B[4*(l>>4)+e][l&15]
//   D frag: lane l reg j  -> D[4*(l>>4)+j][l&15]     (m89-verified mapping)
template <int OUT_HALF>
__global__ __launch_bounds__(256) void hgemm_kernel(
    const f16* __restrict__ A, const f16* __restrict__ Bt,
    void* __restrict__ C, const float* __restrict__ bias,
    int M, int Nn, int K)
{
    __shared__ f16 As[GBM][LDK];
    __shared__ f16 Bs[GBN][LDK];
    const int tid = threadIdx.x;
    const int w = tid >> 6;
    const int l = tid & 63;
    const int brow = blockIdx.y * GBM;
    const int bcol = blockIdx.x * GBN;

    const int sr = tid >> 2;         // staging row 0..63
    const int sc = (tid & 3) * 8;    // staging k-chunk 0/8/16/24

    const int arow = min(brow + sr, M - 1);        // clamp; stores guarded
    const f16* aptr = A + (size_t)arow * K + sc;
    const f16* bptr = Bt + (size_t)(bcol + sr) * K + sc;

    const int fr = l & 15;
    const int k4 = (l >> 4) * 4;

    f32x4 acc[4];
#pragma unroll
    for (int c = 0; c < 4; c++) acc[c] = (f32x4){0.f, 0.f, 0.f, 0.f};

    for (int kk = 0; kk < K; kk += GBK) {
        *(f16x8*)&As[sr][sc] = *(const f16x8*)(aptr + kk);
        *(f16x8*)&Bs[sr][sc] = *(const f16x8*)(bptr + kk);
        __syncthreads();
#pragma unroll
        for (int k0 = 0; k0 < GBK; k0 += 16) {
            f16x4 af = *(const f16x4*)&As[w * 16 + fr][k0 + k4];
#pragma unroll
            for (int c = 0; c < 4; c++) {
                f16x4 bf = *(const f16x4*)&Bs[c * 16 + fr][k0 + k4];
                acc[c] = __builtin_amdgcn_mfma_f32_16x16x16f16(af, bf, acc[c], 0, 0, 0);
            }
        }
        __syncthreads();
    }

#pragma unroll
    for (int c = 0; c < 4; c++) {
        const int col = bcol + c * 16 + fr;
#pragma unroll
        for (int j = 0; j < 4; j++) {
            const int row = brow + w * 16 + (l >> 4) * 4 + j;
            if (row < M) {
                if (OUT_HALF)
                    ((f16*)C)[(size_t)row * Nn + col] = (f16)acc[c][j];
                else
                    ((float*)C)[(size_t)row * Nn + col] = acc[c][j] + bias[col];
            }
        }
    }
}

// ---------------------------------------------------------------------------
// Attention: 1 block per row n, 4 waves = 4 heads. 16-lane groups own keys
// a = g, g+4, ... of 33 (null + 32 gathered, f16 KV table, scale pre-folded
// into Wq). KV row j = [K(256) | V(256)] f16.
// ---------------------------------------------------------------------------
__global__ __launch_bounds__(256) void attn_kernel(
    const f16* __restrict__ Q, const f16* __restrict__ KV,
    const int* __restrict__ aidx, const int* __restrict__ amask,
    const float* __restrict__ nullk, const float* __restrict__ nullv,
    f16* __restrict__ out)
{
    const int n    = blockIdx.x;
    const int tid  = threadIdx.x;
    const int h    = tid >> 6;
    const int lane = tid & 63;
    const int g    = lane >> 4;
    const int gl   = lane & 15;

    __shared__ int sidx[32];
    __shared__ int smask[32];
    if (tid < 32) { sidx[tid] = aidx[n * 32 + tid]; smask[tid] = amask[n * 32 + tid]; }
    __syncthreads();

    f16x4 qh = *(const f16x4*)(Q + (size_t)n * 256 + h * 64 + gl * 4);
    const float q0 = (float)qh[0], q1 = (float)qh[1], q2 = (float)qh[2], q3 = (float)qh[3];

    float sim[9];
#pragma unroll
    for (int r = 0; r < 9; r++) sim[r] = -3.0e38f;

#pragma unroll
    for (int r = 0; r < 9; r++) {
        int a = r * 4 + g;
        if (a < 33) {
            bool doit = false;
            float k0, k1, k2, k3;
            if (a == 0) {
                doit = true;
                float4 k4 = ((const float4*)nullk)[h * 16 + gl];
                // null_k is unscaled; Q was scaled by 0.125 via Wq -> consistent
                k0 = k4.x; k1 = k4.y; k2 = k4.z; k3 = k4.w;
            } else if (smask[a - 1] != 0) {
                doit = true;
                int j = sidx[a - 1];
                f16x4 kh = *(const f16x4*)(KV + (size_t)j * 512 + h * 64 + gl * 4);
                k0 = (float)kh[0]; k1 = (float)kh[1]; k2 = (float)kh[2]; k3 = (float)kh[3];
            }
            if (doit) {
                float s = q0 * k0 + q1 * k1 + q2 * k2 + q3 * k3;
                s += __shfl_xor(s, 1); s += __shfl_xor(s, 2);
                s += __shfl_xor(s, 4); s += __shfl_xor(s, 8);
                sim[r] = s;
            }
        }
    }

    float m = -3.0e38f;
#pragma unroll
    for (int r = 0; r < 9; r++) m = fmaxf(m, sim[r]);
    m = fmaxf(m, __shfl_xor(m, 16));
    m = fmaxf(m, __shfl_xor(m, 32));

    float p[9]; float l = 0.0f;
#pragma unroll
    for (int r = 0; r < 9; r++) {
        p[r] = (sim[r] > -1.0e37f) ? __expf(sim[r] - m) : 0.0f;
        l += p[r];
    }
    l += __shfl_xor(l, 16);
    l += __shfl_xor(l, 32);
    const float inv = 1.0f / l;
#pragma unroll
    for (int r = 0; r < 9; r++) p[r] *= inv;

    float acc = 0.0f;
    const float p0 = __shfl(p[0], 0);
    acc += p0 * nullv[h * 64 + lane];
#pragma unroll
    for (int a = 1; a <= 32; a++) {
        float pa = __shfl(p[a >> 2], (a & 3) << 4);
        if (pa != 0.0f) {                     // wave-uniform; skips masked gathers
            int j = sidx[a - 1];
            acc += pa * (float)KV[(size_t)j * 512 + 256 + h * 64 + lane];
        }
    }
    out[(size_t)n * 256 + h * 64 + lane] = (f16)acc;
}

// ---------------------------------------------------------------------------
extern "C" void kernel_launch(void* const* d_in, const int* in_sizes, int n_in,
                              void* d_out, int out_size, void* d_ws, size_t ws_size,
                              hipStream_t stream)
{
    const float* x     = (const float*)d_in[0];
    const int*   aidx  = (const int*)  d_in[1];
    const int*   amask = (const int*)  d_in[2];
    const float* Wq    = (const float*)d_in[3];
    const float* Wkv   = (const float*)d_in[4];
    const float* Wo    = (const float*)d_in[5];
    const float* bo    = (const float*)d_in[6];
    const float* nk    = (const float*)d_in[7];
    const float* nv    = (const float*)d_in[8];
    float* out = (float*)d_out;

    const int N = 10000;
    f16* xh   = (f16*)d_ws;                    // N*256
    f16* Wqt  = xh   + (size_t)N * 256;        // 256*256 (transposed, x0.125)
    f16* Wkvt = Wqt  + 256 * 256;              // 512*256 (transposed)
    f16* Wot  = Wkvt + 512 * 256;              // 256*256 (transposed)
    f16* Qh   = Wot  + 256 * 256;              // N*256
    f16* KVh  = Qh   + (size_t)N * 256;        // N*512
    f16* AOh  = KVh  + (size_t)N * 512;        // N*256

    dim3 blk(256);
    cast_kernel<<<dim3((N * 256 / 4 + 255) / 256), blk, 0, stream>>>(x, xh, N * 256 / 4);
    tcast_kernel<<<dim3(8,  8), blk, 0, stream>>>(Wq,  Wqt,  256, 256, 0.125f);
    tcast_kernel<<<dim3(16, 8), blk, 0, stream>>>(Wkv, Wkvt, 256, 512, 1.0f);
    tcast_kernel<<<dim3(8,  8), blk, 0, stream>>>(Wo,  Wot,  256, 256, 1.0f);

    const int gm = (N + GBM - 1) / GBM;        // 157
    hgemm_kernel<1><<<dim3(4, gm), blk, 0, stream>>>(xh, Wqt,  Qh,  nullptr, N, 256, 256);
    hgemm_kernel<1><<<dim3(8, gm), blk, 0, stream>>>(xh, Wkvt, KVh, nullptr, N, 512, 256);
    attn_kernel   <<<dim3(N),      blk, 0, stream>>>(Qh, KVh, aidx, amask, nk, nv, AOh);
    hgemm_kernel<0><<<dim3(4, gm), blk, 0, stream>>>(AOh, Wot, out, bo,     N, 256, 256);
}

// Round 8
// 150.150 us; speedup vs baseline: 1.7611x; 1.2207x over previous
//
#include <hip/hip_runtime.h>
#include <float.h>

// ---------------------------------------------------------------------------
// B=1, N=10000, A=32, D=256, H=4, DH=64
// Pipeline: [tcast Wq|Wkv -> Wqkvt] [tcast Wo -> Wot]
//           QKV = x @ [Wq|Wkv]   (f16 MFMA, x cast folded into staging)
//           attn (branchless gathers, mask via select)
//           out = AO @ Wo + bo   (f16 MFMA, f32 out)
// ---------------------------------------------------------------------------

typedef _Float16 f16;
typedef _Float16 f16x4 __attribute__((ext_vector_type(4)));
typedef _Float16 f16x8 __attribute__((ext_vector_type(8)));
typedef float    f32x4 __attribute__((ext_vector_type(4)));

#define BM 64
#define BN 128
#define BK 64
#define LDK 72   // padded f16 k-stride; 144B row pitch -> ~2-way (free) on b64 reads

// W [K][Nn] f32 -> Wt [Nn][K] f16 (scaled). 32x32 LDS tile transpose.
__global__ __launch_bounds__(256) void tcast_kernel(
    const float* __restrict__ W, f16* __restrict__ Wt, int K, int Nn, float mul)
{
    __shared__ float s[32][33];
    const int tx = threadIdx.x & 31, ty = threadIdx.x >> 5;
    const int kb = blockIdx.y * 32, nb = blockIdx.x * 32;
#pragma unroll
    for (int r = 0; r < 4; r++)
        s[ty + r * 8][tx] = W[(size_t)(kb + ty + r * 8) * Nn + nb + tx];
    __syncthreads();
#pragma unroll
    for (int r = 0; r < 4; r++)
        Wt[(size_t)(nb + ty + r * 8) * K + kb + tx] = (f16)(s[tx][ty + r * 8] * mul);
}

// C[M][Nn] = A[M][K] @ Bt[Nn][K]^T (+bias). 256 thr = 4 waves; wave w owns
// rows w*16..+15 x all BN cols. v_mfma_f32_16x16x16_f16 (verified mapping):
//   A: lane l elem e -> A[l&15][4*(l>>4)+e];  B: col l&15, same k
//   D: lane l reg j  -> D[4*(l>>4)+j][l&15]
template <int A_F32, int OUT_HALF>
__global__ __launch_bounds__(256) void hgemm_kernel(
    const void* __restrict__ Av, const f16* __restrict__ Bt,
    void* __restrict__ C, const float* __restrict__ bias,
    int M, int Nn, int K)
{
    __shared__ f16 As[BM][LDK];
    __shared__ f16 Bs[BN][LDK];
    const int tid = threadIdx.x;
    const int w = tid >> 6;
    const int l = tid & 63;
    const int brow = blockIdx.y * BM;
    const int bcol = blockIdx.x * BN;

    const int sra = tid >> 2, sca = (tid & 3) * 16;   // A: 64 rows x 64 k
    const int srb = tid >> 1, scb = (tid & 1) * 32;   // B: 128 rows x 64 k
    const int arow = min(brow + sra, M - 1);          // clamp; stores guarded

    const int fr = l & 15;
    const int k4 = (l >> 4) * 4;

    f32x4 acc[8];
#pragma unroll
    for (int c = 0; c < 8; c++) acc[c] = (f32x4){0.f, 0.f, 0.f, 0.f};

    for (int kk = 0; kk < K; kk += BK) {
        if (A_F32) {
            const float* ap = (const float*)Av + (size_t)arow * K + kk + sca;
#pragma unroll
            for (int i = 0; i < 4; i++) {
                float4 v = ((const float4*)ap)[i];
                f16x4 o = {(f16)v.x, (f16)v.y, (f16)v.z, (f16)v.w};
                *(f16x4*)&As[sra][sca + i * 4] = o;
            }
        } else {
            const f16* ap = (const f16*)Av + (size_t)arow * K + kk + sca;
            *(f16x8*)&As[sra][sca]     = *(const f16x8*)(ap);
            *(f16x8*)&As[sra][sca + 8] = *(const f16x8*)(ap + 8);
        }
        {
            const f16* bp = Bt + (size_t)(bcol + srb) * K + kk + scb;
#pragma unroll
            for (int i = 0; i < 4; i++)
                *(f16x8*)&Bs[srb][scb + i * 8] = *(const f16x8*)(bp + i * 8);
        }
        __syncthreads();
#pragma unroll
        for (int k0 = 0; k0 < BK; k0 += 16) {
            f16x4 af = *(const f16x4*)&As[w * 16 + fr][k0 + k4];
#pragma unroll
            for (int c = 0; c < 8; c++) {
                f16x4 bf = *(const f16x4*)&Bs[c * 16 + fr][k0 + k4];
                acc[c] = __builtin_amdgcn_mfma_f32_16x16x16f16(af, bf, acc[c], 0, 0, 0);
            }
        }
        __syncthreads();
    }

#pragma unroll
    for (int c = 0; c < 8; c++) {
        const int col = bcol + c * 16 + fr;
#pragma unroll
        for (int j = 0; j < 4; j++) {
            const int row = brow + w * 16 + (l >> 4) * 4 + j;
            if (row < M) {
                if (OUT_HALF)
                    ((f16*)C)[(size_t)row * Nn + col] = (f16)acc[c][j];
                else
                    ((float*)C)[(size_t)row * Nn + col] = acc[c][j] + bias[col];
            }
        }
    }
}

// ---------------------------------------------------------------------------
// Attention: block = row n, wave w = head h. 16-lane group g owns keys
// a = g mod 4 of 33 (null + 32). Branchless: K/V loads unconditional (indices
// always valid), mask applied via select on the score / zeroed p.
// QKV row j = [Q(256, pre-scaled) | K(256) | V(256)] f16, stride 768.
// Two block barriers total (idx staging, sP publish) — safe, negligible cost.
// ---------------------------------------------------------------------------
__global__ __launch_bounds__(256) void attn_kernel(
    const f16* __restrict__ QKV,
    const int* __restrict__ aidx, const int* __restrict__ amask,
    const float* __restrict__ nullk, const float* __restrict__ nullv,
    f16* __restrict__ out)
{
    const int n    = blockIdx.x;
    const int tid  = threadIdx.x;
    const int w    = tid >> 6;      // wave = head
    const int h    = w;
    const int lane = tid & 63;
    const int g    = lane >> 4;
    const int gl   = lane & 15;

    __shared__ int   sIdx[32];
    __shared__ int   sMsk[32];
    __shared__ float sP[4][33];

    if (tid < 32) {
        sIdx[tid] = aidx[n * 32 + tid];
        sMsk[tid] = amask[n * 32 + tid];
    }
    __syncthreads();

    f16x4 qh = *(const f16x4*)(QKV + (size_t)n * 768 + h * 64 + gl * 4);
    const float q0 = (float)qh[0], q1 = (float)qh[1], q2 = (float)qh[2], q3 = (float)qh[3];

    float sim[9];

    // round 0: a = g (group 0 = null key; only divergent spot in the kernel)
    {
        float s;
        if (g == 0) {
            float4 nk4 = ((const float4*)nullk)[h * 16 + gl];
            s = q0 * nk4.x + q1 * nk4.y + q2 * nk4.z + q3 * nk4.w;
        } else {
            int j = sIdx[g - 1];
            f16x4 kh = *(const f16x4*)(QKV + (size_t)j * 768 + 256 + h * 64 + gl * 4);
            s = q0 * (float)kh[0] + q1 * (float)kh[1] + q2 * (float)kh[2] + q3 * (float)kh[3];
        }
        s += __shfl_xor(s, 1); s += __shfl_xor(s, 2);
        s += __shfl_xor(s, 4); s += __shfl_xor(s, 8);
        bool ok = (g == 0) || (sMsk[g - 1] != 0);
        sim[0] = ok ? s : -3.0e38f;
    }

    // rounds 1..8: a = r*4+g in [4,35]; branchless, unconditional loads
#pragma unroll
    for (int r = 1; r < 9; r++) {
        int a  = r * 4 + g;
        int ai = min(a - 1, 31);
        int j  = sIdx[ai];
        f16x4 kh = *(const f16x4*)(QKV + (size_t)j * 768 + 256 + h * 64 + gl * 4);
        float s = q0 * (float)kh[0] + q1 * (float)kh[1] + q2 * (float)kh[2] + q3 * (float)kh[3];
        s += __shfl_xor(s, 1); s += __shfl_xor(s, 2);
        s += __shfl_xor(s, 4); s += __shfl_xor(s, 8);
        bool ok = (a < 33) && (sMsk[ai] != 0);
        sim[r] = ok ? s : -3.0e38f;
    }

    // softmax over 33 (groups disjoint; lanes within group identical)
    float m = sim[0];
#pragma unroll
    for (int r = 1; r < 9; r++) m = fmaxf(m, sim[r]);
    m = fmaxf(m, __shfl_xor(m, 16));
    m = fmaxf(m, __shfl_xor(m, 32));

    float p[9]; float l = 0.0f;
#pragma unroll
    for (int r = 0; r < 9; r++) {
        p[r] = (sim[r] > -1.0e37f) ? __expf(sim[r] - m) : 0.0f;
        l += p[r];
    }
    l += __shfl_xor(l, 16);
    l += __shfl_xor(l, 32);
    const float inv = 1.0f / l;

    if (gl == 0) {
#pragma unroll
        for (int r = 0; r < 9; r++) {
            int a = r * 4 + g;
            if (a < 33) sP[w][a] = p[r] * inv;
        }
    }
    __syncthreads();

    // P @ V: lane owns output dim d = lane; all 33 loads unconditional
    float acc = sP[w][0] * nullv[h * 64 + lane];
#pragma unroll
    for (int a = 1; a <= 32; a++) {
        int j = sIdx[a - 1];
        float va = (float)QKV[(size_t)j * 768 + 512 + h * 64 + lane];
        acc += sP[w][a] * va;
    }
    out[(size_t)n * 256 + h * 64 + lane] = (f16)acc;
}

// ---------------------------------------------------------------------------
extern "C" void kernel_launch(void* const* d_in, const int* in_sizes, int n_in,
                              void* d_out, int out_size, void* d_ws, size_t ws_size,
                              hipStream_t stream)
{
    const float* x     = (const float*)d_in[0];
    const int*   aidx  = (const int*)  d_in[1];
    const int*   amask = (const int*)  d_in[2];
    const float* Wq    = (const float*)d_in[3];
    const float* Wkv   = (const float*)d_in[4];
    const float* Wo    = (const float*)d_in[5];
    const float* bo    = (const float*)d_in[6];
    const float* nk    = (const float*)d_in[7];
    const float* nv    = (const float*)d_in[8];
    float* out = (float*)d_out;

    const int N = 10000;
    f16* Wqkvt = (f16*)d_ws;                       // 768*256 (rows 0-255 Wq^T*0.125, 256-767 Wkv^T)
    f16* Wot   = Wqkvt + 768 * 256;                // 256*256
    f16* QKV   = Wot   + 256 * 256;                // N*768
    f16* AOh   = QKV   + (size_t)N * 768;          // N*256

    dim3 blk(256);
    tcast_kernel<<<dim3(8,  8), blk, 0, stream>>>(Wq,  Wqkvt,             256, 256, 0.125f);
    tcast_kernel<<<dim3(16, 8), blk, 0, stream>>>(Wkv, Wqkvt + 256 * 256, 256, 512, 1.0f);
    tcast_kernel<<<dim3(8,  8), blk, 0, stream>>>(Wo,  Wot,               256, 256, 1.0f);

    const int gm = (N + BM - 1) / BM;              // 157
    hgemm_kernel<1, 1><<<dim3(768 / BN, gm), blk, 0, stream>>>(x,   Wqkvt, QKV, nullptr, N, 768, 256);
    attn_kernel       <<<dim3(N),              blk, 0, stream>>>(QKV, aidx, amask, nk, nv, AOh);
    hgemm_kernel<0, 0><<<dim3(256 / BN, gm), blk, 0, stream>>>(AOh, Wot,   out, bo,      N, 256, 256);
}